// Round 8
// baseline (828.465 us; speedup 1.0000x reference)
//
#include <hip/hip_runtime.h>
#include <hip/hip_cooperative_groups.h>
#include <hip/hip_bf16.h>
#include <math.h>

namespace cg = cooperative_groups;

// AttnBlock: B=16, C=256, H=W=64, heads=4, dim_head=32
#define BATCH 16
#define CH 256
#define NPOS 4096
#define INNER 128
#define HEADS 4
#define DH 32

typedef __hip_bfloat16 bf16;
typedef short bf8v __attribute__((ext_vector_type(8)));    // 8 bf16 (4 VGPRs)
typedef float f32x4 __attribute__((ext_vector_type(4)));

__device__ __forceinline__ float b2f(bf16 v) { return __bfloat162float(v); }
__device__ __forceinline__ float us2f(unsigned short u) {
    unsigned w = ((unsigned)u) << 16; float f; __builtin_memcpy(&f, &w, 4); return f;
}
__device__ __forceinline__ unsigned short f2us(float f) {
    bf16 h = __float2bfloat16(f); unsigned short u; __builtin_memcpy(&u, &h, 2); return u;
}
__device__ __forceinline__ bf16 f2b(float v) { return __float2bfloat16(v); }

// ===========================================================================
// MEGA (cooperative): W-prep + LN + q/k/v GEMM + ctx + reduce/wmod + y-GEMM +
// LN + residual, with grid.sync() at the 3 global dependency points.
// grid = 1024 blocks (= 4/CU x 256 CU exactly), 256 thr, LDS 39424 B,
// launch_bounds(256,4) => VGPR<=128 => co-resident by construction.
// ppack (q softmax result) lives in 16 VGPRs across the syncs: K4's x
// re-stage (64 MB) and duplicate q-GEMM are gone.
// ===========================================================================
__global__ __launch_bounds__(256, 4)
void mega_kernel(const float* __restrict__ x, const float* __restrict__ Wqkv,
                 const float* __restrict__ Wout, const float* __restrict__ bout,
                 float* __restrict__ out,
                 bf16* __restrict__ wqb, float* __restrict__ wqs,
                 float* __restrict__ ctxp, bf16* __restrict__ wmod) {
    __shared__ char smem[36864];       // A[64][264] bf16 U 4x{ekt,vt}[32][72] U cs U Ap/ct
    __shared__ float stats[640];       // LN partials + mu/rs ; reused as y-LN st
    cg::grid_group grid = cg::this_grid();

    const int bid = blockIdx.x;
    const int b = bid >> 6, tile = bid & 63, n0 = tile * 64;
    const int tid = threadIdx.x;
    const int w = tid >> 6, lane = tid & 63;
    const int lrow = lane & 15, kq = lane >> 4;
    bf16* A = (bf16*)smem;             // [64][264]

    // ---- W prep (blocks 0..95): Wqkv fp32 -> bf16 + per-row colsum ----
    if (bid < 96) {
        int idx = (bid * 256 + tid) * 4;
        float4 wv4 = *(const float4*)&Wqkv[idx];
        ushort4 u;
        u.x = f2us(wv4.x); u.y = f2us(wv4.y); u.z = f2us(wv4.z); u.w = f2us(wv4.w);
        *(ushort4*)&wqb[idx] = u;
        float s4 = us2f(u.x) + us2f(u.y) + us2f(u.z) + us2f(u.w);
        #pragma unroll
        for (int m = 1; m <= 32; m <<= 1) s4 += __shfl_xor(s4, m, 64);
        if (lane == 0) wqs[bid * 4 + w] = s4;
    }

    // ---- stage x tile (raw bf16): float4 along n, fp32 LN partial stats ----
    {
        const int nq = tid & 15, cp = tid >> 4;
        float s[4] = {0.f,0.f,0.f,0.f}, sq[4] = {0.f,0.f,0.f,0.f};
        #pragma unroll
        for (int i = 0; i < 8; ++i) {
            int c0 = cp * 2 + 32 * i;
            const float* xp = x + ((size_t)b * CH + c0) * NPOS + n0 + nq * 4;
            float4 fa = *(const float4*)xp;
            float4 fb = *(const float4*)(xp + NPOS);
            #pragma unroll
            for (int j = 0; j < 4; ++j) {
                float va = (&fa.x)[j], vb = (&fb.x)[j];
                s[j] += va + vb; sq[j] += va * va + vb * vb;
                *(unsigned*)&A[(nq * 4 + j) * 264 + c0] =
                    (unsigned)f2us(va) | ((unsigned)f2us(vb) << 16);
            }
        }
        #pragma unroll
        for (int j = 0; j < 4; ++j) {
            s[j]  += __shfl_xor(s[j], 16, 64);  sq[j] += __shfl_xor(sq[j], 16, 64);
            s[j]  += __shfl_xor(s[j], 32, 64);  sq[j] += __shfl_xor(sq[j], 32, 64);
            if (lane < 16) {
                stats[(nq * 4 + j) * 8 + w * 2]     = s[j];
                stats[(nq * 4 + j) * 8 + w * 2 + 1] = sq[j];
            }
        }
    }
    __syncthreads();
    if (tid < 64) {
        float s  = stats[tid*8] + stats[tid*8+2] + stats[tid*8+4] + stats[tid*8+6];
        float sq = stats[tid*8+1] + stats[tid*8+3] + stats[tid*8+5] + stats[tid*8+7];
        float m = s * (1.f / 256.f);
        float var = sq * (1.f / 256.f) - m * m;
        stats[512 + tid * 2] = m;
        stats[512 + tid * 2 + 1] = rsqrtf(var + 1e-5f);
    }
    __syncthreads();

    __threadfence();
    grid.sync();                       // wqb/wqs visible everywhere

    // ---- q-GEMM (head == wave) + in-register softmax -> ppack (regs) ----
    unsigned ppack[4][4];
    {
        const bf16* wp = wqb + (size_t)(w * 32) * 256;
        const float cs0 = wqs[w * 32 + lrow];
        const float cs1 = wqs[w * 32 + 16 + lrow];
        f32x4 qacc[4][2];
        #pragma unroll
        for (int i = 0; i < 4; ++i) {
            qacc[i][0] = (f32x4){0.f,0.f,0.f,0.f};
            qacc[i][1] = (f32x4){0.f,0.f,0.f,0.f};
        }
        #pragma unroll 4
        for (int k0 = 0; k0 < 256; k0 += 32) {
            bf8v af[4], bfr[2];
            #pragma unroll
            for (int t = 0; t < 4; ++t)
                af[t] = *(const bf8v*)&A[(t * 16 + lrow) * 264 + k0 + kq * 8];
            #pragma unroll
            for (int t = 0; t < 2; ++t)
                bfr[t] = *(const bf8v*)&wp[(size_t)(t * 16 + lrow) * 256 + k0 + kq * 8];
            #pragma unroll
            for (int mt = 0; mt < 4; ++mt)
                #pragma unroll
                for (int nt = 0; nt < 2; ++nt)
                    qacc[mt][nt] = __builtin_amdgcn_mfma_f32_16x16x32_bf16(
                        af[mt], bfr[nt], qacc[mt][nt], 0, 0, 0);
        }
        #pragma unroll
        for (int mt = 0; mt < 4; ++mt)
            #pragma unroll
            for (int r = 0; r < 4; ++r) {
                int row = mt * 16 + kq * 4 + r;
                float mu = stats[512 + row * 2], rsn = stats[512 + row * 2 + 1];
                float e0 = __expf(b2f(f2b((qacc[mt][0][r] - mu * cs0) * rsn)));
                float e1 = __expf(b2f(f2b((qacc[mt][1][r] - mu * cs1) * rsn)));
                float s = e0 + e1;
                s += __shfl_xor(s, 1, 64);  s += __shfl_xor(s, 2, 64);
                s += __shfl_xor(s, 4, 64);  s += __shfl_xor(s, 8, 64);
                float rd = 1.f / s;
                ppack[mt][r] = (unsigned)f2us(e0 * rd) | ((unsigned)f2us(e1 * rd) << 16);
            }
    }

    // ---- k/v GEMMs + per-tile ctx partial ----
    {
        ushort4 ekp[4][2];
        float se0 = 0.f, se1 = 0.f;
        for (int ph = 1; ph < 3; ++ph) {
            const bf16* wp = wqb + (size_t)(ph * 128 + w * 32) * 256;
            const float cs0 = wqs[ph * 128 + w * 32 + lrow];
            const float cs1 = wqs[ph * 128 + w * 32 + 16 + lrow];
            f32x4 acc[4][2];
            #pragma unroll
            for (int i = 0; i < 4; ++i) {
                acc[i][0] = (f32x4){0.f,0.f,0.f,0.f};
                acc[i][1] = (f32x4){0.f,0.f,0.f,0.f};
            }
            #pragma unroll 4
            for (int k0 = 0; k0 < 256; k0 += 32) {
                bf8v af[4], bfr[2];
                #pragma unroll
                for (int t = 0; t < 4; ++t)
                    af[t] = *(const bf8v*)&A[(t * 16 + lrow) * 264 + k0 + kq * 8];
                #pragma unroll
                for (int t = 0; t < 2; ++t)
                    bfr[t] = *(const bf8v*)&wp[(size_t)(t * 16 + lrow) * 256 + k0 + kq * 8];
                #pragma unroll
                for (int mt = 0; mt < 4; ++mt)
                    #pragma unroll
                    for (int nt = 0; nt < 2; ++nt)
                        acc[mt][nt] = __builtin_amdgcn_mfma_f32_16x16x32_bf16(
                            af[mt], bfr[nt], acc[mt][nt], 0, 0, 0);
            }

            if (ph == 1) {
                se0 = 0.f; se1 = 0.f;
                #pragma unroll
                for (int mt = 0; mt < 4; ++mt) {
                    ushort4 u0, u1;
                    unsigned short q_;
                    #pragma unroll
                    for (int r = 0; r < 4; ++r) {
                        int row = mt * 16 + kq * 4 + r;
                        float mu = stats[512 + row * 2], rsn = stats[512 + row * 2 + 1];
                        q_ = f2us(__expf(b2f(f2b((acc[mt][0][r] - mu * cs0) * rsn))));
                        se0 += us2f(q_); (&u0.x)[r] = q_;
                        q_ = f2us(__expf(b2f(f2b((acc[mt][1][r] - mu * cs1) * rsn))));
                        se1 += us2f(q_); (&u1.x)[r] = q_;
                    }
                    ekp[mt][0] = u0; ekp[mt][1] = u1;
                }
                se0 += __shfl_xor(se0, 16, 64); se0 += __shfl_xor(se0, 32, 64);
                se1 += __shfl_xor(se1, 16, 64); se1 += __shfl_xor(se1, 32, 64);
            } else {
                __syncthreads();       // A dead from here (q/k done)
                bf16* ekt = (bf16*)(smem + w * 9216);          // [32][72]
                bf16* vt  = (bf16*)(smem + w * 9216 + 4608);   // [32][72]
                #pragma unroll
                for (int mt = 0; mt < 4; ++mt)
                    #pragma unroll
                    for (int nt = 0; nt < 2; ++nt) {
                        float csx = nt ? cs1 : cs0;
                        ushort4 vv;
                        #pragma unroll
                        for (int r = 0; r < 4; ++r) {
                            int row = mt * 16 + kq * 4 + r;
                            float mu = stats[512 + row * 2], rsn = stats[512 + row * 2 + 1];
                            (&vv.x)[r] = f2us((acc[mt][nt][r] - mu * csx) * rsn);
                        }
                        int d = nt * 16 + lrow, n = mt * 16 + kq * 4;
                        *(ushort4*)&vt[d * 72 + n]  = vv;
                        *(ushort4*)&ekt[d * 72 + n] = ekp[mt][nt];
                    }
                f32x4 cacc[2][2];
                cacc[0][0] = (f32x4){0.f,0.f,0.f,0.f}; cacc[0][1] = cacc[0][0];
                cacc[1][0] = cacc[0][0];               cacc[1][1] = cacc[0][0];
                #pragma unroll
                for (int ks = 0; ks < 2; ++ks) {
                    bf8v a2[2], bv2[2];
                    a2[0]  = *(const bf8v*)&ekt[lrow * 72 + ks * 32 + kq * 8];
                    a2[1]  = *(const bf8v*)&ekt[(16 + lrow) * 72 + ks * 32 + kq * 8];
                    bv2[0] = *(const bf8v*)&vt[lrow * 72 + ks * 32 + kq * 8];
                    bv2[1] = *(const bf8v*)&vt[(16 + lrow) * 72 + ks * 32 + kq * 8];
                    #pragma unroll
                    for (int mt2 = 0; mt2 < 2; ++mt2)
                        #pragma unroll
                        for (int nt2 = 0; nt2 < 2; ++nt2)
                            cacc[mt2][nt2] = __builtin_amdgcn_mfma_f32_16x16x32_bf16(
                                a2[mt2], bv2[nt2], cacc[mt2][nt2], 0, 0, 0);
                }
                float* pb = ctxp + ((size_t)(b * 64 + tile) * 4 + w) * 1056;
                #pragma unroll
                for (int mt2 = 0; mt2 < 2; ++mt2)
                    #pragma unroll
                    for (int nt2 = 0; nt2 < 2; ++nt2)
                        #pragma unroll
                        for (int r = 0; r < 4; ++r) {
                            int d = mt2 * 16 + kq * 4 + r, e = nt2 * 16 + lrow;
                            pb[d * 32 + e] = cacc[mt2][nt2][r];
                        }
                if (kq == 0) {
                    pb[1024 + lrow] = se0;
                    pb[1024 + 16 + lrow] = se1;
                }
            }
        }
    }

    __threadfence();
    grid.sync();                       // ctxp complete

    // ---- phase B (blocks 0..127): reduce ctxp -> wmod ----
    if (bid < 128) {
        int h = bid & 3, bb = (bid >> 2) & 15, ch = bid >> 6;
        float* cs = (float*)smem;      // 1056 floats (A region dead)
        #pragma unroll
        for (int i = 0; i < 2; ++i) {
            int s = i * 256 + tid;
            if (s < 264) {
                f32x4 a = (f32x4){0.f,0.f,0.f,0.f};
                const float* src = ctxp + (size_t)(bb * 256 + h) * 1056 + s * 4;
                for (int t = 0; t < 64; ++t)
                    a += *(const f32x4*)(src + (size_t)t * 4 * 1056);
                *(f32x4*)&cs[s * 4] = a;
            }
        }
        __syncthreads();
        int c = ch * 128 + (tid >> 1);
        int dh2 = tid & 1;
        const float* wr = Wout + (size_t)c * INNER + h * DH;
        float wv[32];
        #pragma unroll
        for (int i = 0; i < 8; ++i) {
            float4 t = *(const float4*)&wr[i * 4];
            wv[i*4] = t.x; wv[i*4+1] = t.y; wv[i*4+2] = t.z; wv[i*4+3] = t.w;
        }
        const float SCALE = 4.3158341e-05f;     // 1/(4096*sqrt(32))
        unsigned* wm32 = (unsigned*)(wmod + ((size_t)bb * CH + c) * INNER + h * DH);
        #pragma unroll
        for (int dd = 0; dd < 8; ++dd) {
            int d1 = dh2 * 8 + dd, d2 = d1 + 16;
            const float* c1 = &cs[d1 * 32];
            const float* c2 = &cs[d2 * 32];
            float s1 = 0.f, s2 = 0.f;
            #pragma unroll
            for (int e4 = 0; e4 < 8; ++e4) {
                f32x4 t1 = *(const f32x4*)&c1[e4 * 4];
                f32x4 t2 = *(const f32x4*)&c2[e4 * 4];
                #pragma unroll
                for (int j = 0; j < 4; ++j) {
                    s1 += wv[e4 * 4 + j] * t1[j];
                    s2 += wv[e4 * 4 + j] * t2[j];
                }
            }
            float v1 = s1 * SCALE / cs[1024 + d1];
            float v2 = s2 * SCALE / cs[1024 + d2];
            wm32[d1] = (unsigned)f2us(v1) | ((unsigned)f2us(v2) << 16);
        }
    }

    __threadfence();
    grid.sync();                       // wmod complete

    // ---- phase C: y-GEMM from ppack (LDS) + wmod, LN, residual, out ----
    bf16* Ap = (bf16*)smem;            // [64][136]
    float* ct = (float*)smem;          // [128][68]
    float* st = stats;                 // reuse (dead)
    {
        unsigned* Ap32 = (unsigned*)Ap;
        #pragma unroll
        for (int mt = 0; mt < 4; ++mt)
            #pragma unroll
            for (int r = 0; r < 4; ++r) {
                int row = mt * 16 + kq * 4 + r;
                Ap32[row * 68 + w * 16 + lrow] = ppack[mt][r];
            }
    }
    __syncthreads();

    f32x4 acc[4][4];
    #pragma unroll
    for (int i = 0; i < 4; ++i)
        #pragma unroll
        for (int j = 0; j < 4; ++j) acc[i][j] = (f32x4){0.f, 0.f, 0.f, 0.f};

    const bf16* wb = wmod + (size_t)b * CH * INNER + (size_t)(w * 64) * INNER;
    #pragma unroll 2
    for (int k0 = 0; k0 < 128; k0 += 32) {
        bf8v af[4], bfr[4];
        #pragma unroll
        for (int t = 0; t < 4; ++t)
            af[t] = *(const bf8v*)&Ap[(t * 16 + lrow) * 136 + k0 + kq * 8];
        #pragma unroll
        for (int t = 0; t < 4; ++t)
            bfr[t] = *(const bf8v*)&wb[(size_t)(t * 16 + lrow) * 128 + k0 + kq * 8];
        #pragma unroll
        for (int mt = 0; mt < 4; ++mt)
            #pragma unroll
            for (int nt = 0; nt < 4; ++nt)
                acc[mt][nt] = __builtin_amdgcn_mfma_f32_16x16x32_bf16(
                    af[mt], bfr[nt], acc[mt][nt], 0, 0, 0);
    }

    #pragma unroll
    for (int nt = 0; nt < 4; ++nt) {
        float bv = bout[w * 64 + nt * 16 + lrow];
        #pragma unroll
        for (int mt = 0; mt < 4; ++mt)
            #pragma unroll
            for (int r = 0; r < 4; ++r) acc[mt][nt][r] += bv;
    }

    #pragma unroll
    for (int mt = 0; mt < 4; ++mt)
        #pragma unroll
        for (int r = 0; r < 4; ++r) {
            float s = 0.f, sq = 0.f;
            #pragma unroll
            for (int nt = 0; nt < 4; ++nt) {
                float v = acc[mt][nt][r];
                s += v; sq += v * v;
            }
            #pragma unroll
            for (int m = 1; m <= 8; m <<= 1) {
                s += __shfl_xor(s, m, 64);
                sq += __shfl_xor(sq, m, 64);
            }
            if (lrow == 0) {
                int row = mt * 16 + kq * 4 + r;
                st[w * 128 + row * 2] = s;
                st[w * 128 + row * 2 + 1] = sq;
            }
        }
    __syncthreads();
    if (tid < 64) {
        float s  = st[tid * 2]       + st[128 + tid * 2]
                 + st[256 + tid * 2] + st[384 + tid * 2];
        float sq = st[tid * 2 + 1]       + st[128 + tid * 2 + 1]
                 + st[256 + tid * 2 + 1] + st[384 + tid * 2 + 1];
        float m = s * (1.f / 256.f);
        float var = sq * (1.f / 256.f) - m * m;
        st[512 + tid * 2] = m;
        st[512 + tid * 2 + 1] = rsqrtf(var + 1e-5f);
    }
    __syncthreads();
    #pragma unroll
    for (int mt = 0; mt < 4; ++mt)
        #pragma unroll
        for (int r = 0; r < 4; ++r) {
            int row = mt * 16 + kq * 4 + r;
            float m = st[512 + row * 2], rs = st[512 + row * 2 + 1];
            #pragma unroll
            for (int nt = 0; nt < 4; ++nt)
                acc[mt][nt][r] = (acc[mt][nt][r] - m) * rs;
        }

    #pragma unroll 1
    for (int pr = 0; pr < 2; ++pr) {
        __syncthreads();
        if ((w >> 1) == pr) {
            #pragma unroll
            for (int mt = 0; mt < 4; ++mt)
                #pragma unroll
                for (int nt = 0; nt < 4; ++nt)
                    #pragma unroll
                    for (int r = 0; r < 4; ++r)
                        ct[((w & 1) * 64 + nt * 16 + lrow) * 68 + mt * 16 + kq * 4 + r]
                            = acc[mt][nt][r];
        }
        __syncthreads();
        #pragma unroll
        for (int i = 0; i < 8; ++i) {
            int idx = i * 256 + tid;
            int n4 = (idx & 15) * 4, cl = idx >> 4;
            size_t gi = ((size_t)b * CH + pr * 128 + cl) * NPOS + n0 + n4;
            f32x4 cv = *(const f32x4*)&ct[cl * 68 + n4];
            f32x4 xv = *(const f32x4*)&x[gi];
            __builtin_nontemporal_store(cv + xv, (f32x4*)&out[gi]);
        }
    }
}

// ===========================================================================
// Fallback path (exact R7 pipeline) — used only if cooperative launch fails.
// ===========================================================================
__global__ __launch_bounds__(256)
void prep_w_kernel(const float* __restrict__ Wqkv, bf16* __restrict__ wqb,
                   float* __restrict__ wqs) {
    int idx = (blockIdx.x * 256 + threadIdx.x) * 4;
    float4 w = *(const float4*)&Wqkv[idx];
    ushort4 u;
    u.x = f2us(w.x); u.y = f2us(w.y); u.z = f2us(w.z); u.w = f2us(w.w);
    *(ushort4*)&wqb[idx] = u;
    float s4 = us2f(u.x) + us2f(u.y) + us2f(u.z) + us2f(u.w);
    #pragma unroll
    for (int m = 1; m <= 32; m <<= 1) s4 += __shfl_xor(s4, m, 64);
    if ((threadIdx.x & 63) == 0)
        wqs[blockIdx.x * 4 + (threadIdx.x >> 6)] = s4;
}

__global__ __launch_bounds__(256)
void fused_qkv_kernel(const float* __restrict__ x, const bf16* __restrict__ wqb,
                      const float* __restrict__ wqs, float* __restrict__ musr,
                      float* __restrict__ ctxp) {
    __shared__ char smem[36864];
    __shared__ float stats[640];

    const int b = blockIdx.y, tile = blockIdx.x, n0 = tile * 64;
    const int tid = threadIdx.x;
    const int w = tid >> 6, lane = tid & 63;
    const int lrow = lane & 15, kq = lane >> 4;
    bf16* A = (bf16*)smem;

    {
        const int nq = tid & 15, cp = tid >> 4;
        float s[4] = {0.f,0.f,0.f,0.f}, sq[4] = {0.f,0.f,0.f,0.f};
        #pragma unroll
        for (int i = 0; i < 8; ++i) {
            int c0 = cp * 2 + 32 * i;
            const float* xp = x + ((size_t)b * CH + c0) * NPOS + n0 + nq * 4;
            float4 fa = *(const float4*)xp;
            float4 fb = *(const float4*)(xp + NPOS);
            #pragma unroll
            for (int j = 0; j < 4; ++j) {
                float va = (&fa.x)[j], vb = (&fb.x)[j];
                s[j] += va + vb; sq[j] += va * va + vb * vb;
                *(unsigned*)&A[(nq * 4 + j) * 264 + c0] =
                    (unsigned)f2us(va) | ((unsigned)f2us(vb) << 16);
            }
        }
        #pragma unroll
        for (int j = 0; j < 4; ++j) {
            s[j]  += __shfl_xor(s[j], 16, 64);  sq[j] += __shfl_xor(sq[j], 16, 64);
            s[j]  += __shfl_xor(s[j], 32, 64);  sq[j] += __shfl_xor(sq[j], 32, 64);
            if (lane < 16) {
                stats[(nq * 4 + j) * 8 + w * 2]     = s[j];
                stats[(nq * 4 + j) * 8 + w * 2 + 1] = sq[j];
            }
        }
    }
    __syncthreads();
    if (tid < 64) {
        float s  = stats[tid*8] + stats[tid*8+2] + stats[tid*8+4] + stats[tid*8+6];
        float sq = stats[tid*8+1] + stats[tid*8+3] + stats[tid*8+5] + stats[tid*8+7];
        float m = s * (1.f / 256.f);
        float var = sq * (1.f / 256.f) - m * m;
        stats[512 + tid * 2] = m;
        stats[512 + tid * 2 + 1] = rsqrtf(var + 1e-5f);
        float2 ms; ms.x = m; ms.y = stats[512 + tid * 2 + 1];
        *(float2*)&musr[((size_t)b * NPOS + n0 + tid) * 2] = ms;
    }
    __syncthreads();

    ushort4 ekp[4][2];
    float se0 = 0.f, se1 = 0.f;

    for (int ph = 1; ph < 3; ++ph) {
        const bf16* wp = wqb + (size_t)(ph * 128 + w * 32) * 256;
        const float cs0 = wqs[ph * 128 + w * 32 + lrow];
        const float cs1 = wqs[ph * 128 + w * 32 + 16 + lrow];
        f32x4 acc[4][2];
        #pragma unroll
        for (int i = 0; i < 4; ++i) {
            acc[i][0] = (f32x4){0.f,0.f,0.f,0.f};
            acc[i][1] = (f32x4){0.f,0.f,0.f,0.f};
        }
        #pragma unroll 4
        for (int k0 = 0; k0 < 256; k0 += 32) {
            bf8v af[4], bfr[2];
            #pragma unroll
            for (int t = 0; t < 4; ++t)
                af[t] = *(const bf8v*)&A[(t * 16 + lrow) * 264 + k0 + kq * 8];
            #pragma unroll
            for (int t = 0; t < 2; ++t)
                bfr[t] = *(const bf8v*)&wp[(size_t)(t * 16 + lrow) * 256 + k0 + kq * 8];
            #pragma unroll
            for (int mt = 0; mt < 4; ++mt)
                #pragma unroll
                for (int nt = 0; nt < 2; ++nt)
                    acc[mt][nt] = __builtin_amdgcn_mfma_f32_16x16x32_bf16(
                        af[mt], bfr[nt], acc[mt][nt], 0, 0, 0);
        }

        if (ph == 1) {
            se0 = 0.f; se1 = 0.f;
            #pragma unroll
            for (int mt = 0; mt < 4; ++mt) {
                ushort4 u0, u1;
                unsigned short q_;
                #pragma unroll
                for (int r = 0; r < 4; ++r) {
                    int row = mt * 16 + kq * 4 + r;
                    float mu = stats[512 + row * 2], rsn = stats[512 + row * 2 + 1];
                    q_ = f2us(__expf(b2f(f2b((acc[mt][0][r] - mu * cs0) * rsn))));
                    se0 += us2f(q_); (&u0.x)[r] = q_;
                    q_ = f2us(__expf(b2f(f2b((acc[mt][1][r] - mu * cs1) * rsn))));
                    se1 += us2f(q_); (&u1.x)[r] = q_;
                }
                ekp[mt][0] = u0; ekp[mt][1] = u1;
            }
            se0 += __shfl_xor(se0, 16, 64); se0 += __shfl_xor(se0, 32, 64);
            se1 += __shfl_xor(se1, 16, 64); se1 += __shfl_xor(se1, 32, 64);
        } else {
            __syncthreads();
            bf16* ekt = (bf16*)(smem + w * 9216);
            bf16* vt  = (bf16*)(smem + w * 9216 + 4608);
            #pragma unroll
            for (int mt = 0; mt < 4; ++mt)
                #pragma unroll
                for (int nt = 0; nt < 2; ++nt) {
                    float csx = nt ? cs1 : cs0;
                    ushort4 vv;
                    #pragma unroll
                    for (int r = 0; r < 4; ++r) {
                        int row = mt * 16 + kq * 4 + r;
                        float mu = stats[512 + row * 2], rsn = stats[512 + row * 2 + 1];
                        (&vv.x)[r] = f2us((acc[mt][nt][r] - mu * csx) * rsn);
                    }
                    int d = nt * 16 + lrow, n = mt * 16 + kq * 4;
                    *(ushort4*)&vt[d * 72 + n]  = vv;
                    *(ushort4*)&ekt[d * 72 + n] = ekp[mt][nt];
                }
            f32x4 cacc[2][2];
            cacc[0][0] = (f32x4){0.f,0.f,0.f,0.f}; cacc[0][1] = cacc[0][0];
            cacc[1][0] = cacc[0][0];               cacc[1][1] = cacc[0][0];
            #pragma unroll
            for (int ks = 0; ks < 2; ++ks) {
                bf8v a2[2], bv2[2];
                a2[0]  = *(const bf8v*)&ekt[lrow * 72 + ks * 32 + kq * 8];
                a2[1]  = *(const bf8v*)&ekt[(16 + lrow) * 72 + ks * 32 + kq * 8];
                bv2[0] = *(const bf8v*)&vt[lrow * 72 + ks * 32 + kq * 8];
                bv2[1] = *(const bf8v*)&vt[(16 + lrow) * 72 + ks * 32 + kq * 8];
                #pragma unroll
                for (int mt2 = 0; mt2 < 2; ++mt2)
                    #pragma unroll
                    for (int nt2 = 0; nt2 < 2; ++nt2)
                        cacc[mt2][nt2] = __builtin_amdgcn_mfma_f32_16x16x32_bf16(
                            a2[mt2], bv2[nt2], cacc[mt2][nt2], 0, 0, 0);
            }
            float* pb = ctxp + ((size_t)(b * 64 + tile) * 4 + w) * 1056;
            #pragma unroll
            for (int mt2 = 0; mt2 < 2; ++mt2)
                #pragma unroll
                for (int nt2 = 0; nt2 < 2; ++nt2)
                    #pragma unroll
                    for (int r = 0; r < 4; ++r) {
                        int d = mt2 * 16 + kq * 4 + r, e = nt2 * 16 + lrow;
                        pb[d * 32 + e] = cacc[mt2][nt2][r];
                    }
            if (kq == 0) {
                pb[1024 + lrow] = se0;
                pb[1024 + 16 + lrow] = se1;
            }
        }
    }
}

__global__ __launch_bounds__(256)
void ctx_wmod_kernel(const float* __restrict__ ctxp, const float* __restrict__ Wout,
                     bf16* __restrict__ wmod) {
    __shared__ float cs[1056];
    int h = blockIdx.x, b = blockIdx.y, ch = blockIdx.z;
    int tid = threadIdx.x;

    #pragma unroll
    for (int i = 0; i < 2; ++i) {
        int s = i * 256 + tid;
        if (s < 264) {
            f32x4 a = (f32x4){0.f,0.f,0.f,0.f};
            const float* src = ctxp + (size_t)(b * 256 + h) * 1056 + s * 4;
            for (int t = 0; t < 64; ++t)
                a += *(const f32x4*)(src + (size_t)t * 4 * 1056);
            *(f32x4*)&cs[s * 4] = a;
        }
    }
    __syncthreads();

    int c = ch * 128 + (tid >> 1);
    int dh = tid & 1;
    const float* wr = Wout + (size_t)c * INNER + h * DH;
    float wv[32];
    #pragma unroll
    for (int i = 0; i < 8; ++i) {
        float4 t = *(const float4*)&wr[i * 4];
        wv[i * 4] = t.x; wv[i * 4 + 1] = t.y; wv[i * 4 + 2] = t.z; wv[i * 4 + 3] = t.w;
    }
    const float SCALE = 4.3158341e-05f;
    unsigned* wm32 = (unsigned*)(wmod + ((size_t)b * CH + c) * INNER + h * DH);
    #pragma unroll
    for (int dd = 0; dd < 8; ++dd) {
        int d1 = dh * 8 + dd, d2 = d1 + 16;
        const float* c1 = &cs[d1 * 32];
        const float* c2 = &cs[d2 * 32];
        float s1 = 0.f, s2 = 0.f;
        #pragma unroll
        for (int e4 = 0; e4 < 8; ++e4) {
            f32x4 t1 = *(const f32x4*)&c1[e4 * 4];
            f32x4 t2 = *(const f32x4*)&c2[e4 * 4];
            #pragma unroll
            for (int j = 0; j < 4; ++j) {
                s1 += wv[e4 * 4 + j] * t1[j];
                s2 += wv[e4 * 4 + j] * t2[j];
            }
        }
        float v1 = s1 * SCALE / cs[1024 + d1];
        float v2 = s2 * SCALE / cs[1024 + d2];
        wm32[d1] = (unsigned)f2us(v1) | ((unsigned)f2us(v2) << 16);
    }
}

__global__ __launch_bounds__(256)
void fused_out_kernel(const bf16* __restrict__ wqb, const float* __restrict__ wqs,
                      const float* __restrict__ musr, const bf16* __restrict__ wmod,
                      const float* __restrict__ bout, const float* __restrict__ x,
                      float* __restrict__ out) {
    __shared__ char lds[37376];
    bf16* A  = (bf16*)lds;
    float* mus = (float*)(lds + 33792);
    bf16* Ap = (bf16*)lds;
    float* ct = (float*)lds;
    float* st = (float*)(lds + 34816);

    const int b = blockIdx.y, n0 = blockIdx.x * 64;
    const int tid = threadIdx.x;
    const int w = tid >> 6, lane = tid & 63;
    const int lrow = lane & 15, kq = lane >> 4;

    {
        const int nq = tid & 15, cp = tid >> 4;
        #pragma unroll
        for (int i = 0; i < 8; ++i) {
            int c0 = cp * 2 + 32 * i;
            const float* xp = x + ((size_t)b * CH + c0) * NPOS + n0 + nq * 4;
            float4 fa = *(const float4*)xp;
            float4 fb = *(const float4*)(xp + NPOS);
            #pragma unroll
            for (int j = 0; j < 4; ++j)
                *(unsigned*)&A[(nq * 4 + j) * 264 + c0] =
                    (unsigned)f2us((&fa.x)[j]) | ((unsigned)f2us((&fb.x)[j]) << 16);
        }
    }
    if (tid < 64) {
        float2 ms = *(const float2*)&musr[((size_t)b * NPOS + n0 + tid) * 2];
        mus[tid * 2] = ms.x; mus[tid * 2 + 1] = ms.y;
    }
    __syncthreads();

    unsigned ppack[4][4];
    {
        const bf16* wp = wqb + (size_t)(w * 32) * 256;
        const float cs0 = wqs[w * 32 + lrow];
        const float cs1 = wqs[w * 32 + 16 + lrow];
        f32x4 qacc[4][2];
        #pragma unroll
        for (int i = 0; i < 4; ++i) {
            qacc[i][0] = (f32x4){0.f,0.f,0.f,0.f};
            qacc[i][1] = (f32x4){0.f,0.f,0.f,0.f};
        }
        #pragma unroll 4
        for (int k0 = 0; k0 < 256; k0 += 32) {
            bf8v af[4], bfr[2];
            #pragma unroll
            for (int t = 0; t < 4; ++t)
                af[t] = *(const bf8v*)&A[(t * 16 + lrow) * 264 + k0 + kq * 8];
            #pragma unroll
            for (int t = 0; t < 2; ++t)
                bfr[t] = *(const bf8v*)&wp[(size_t)(t * 16 + lrow) * 256 + k0 + kq * 8];
            #pragma unroll
            for (int mt = 0; mt < 4; ++mt)
                #pragma unroll
                for (int nt = 0; nt < 2; ++nt)
                    qacc[mt][nt] = __builtin_amdgcn_mfma_f32_16x16x32_bf16(
                        af[mt], bfr[nt], qacc[mt][nt], 0, 0, 0);
        }
        #pragma unroll
        for (int mt = 0; mt < 4; ++mt)
            #pragma unroll
            for (int r = 0; r < 4; ++r) {
                int row = mt * 16 + kq * 4 + r;
                float mu = mus[row * 2], rsn = mus[row * 2 + 1];
                float e0 = __expf(b2f(f2b((qacc[mt][0][r] - mu * cs0) * rsn)));
                float e1 = __expf(b2f(f2b((qacc[mt][1][r] - mu * cs1) * rsn)));
                float s = e0 + e1;
                s += __shfl_xor(s, 1, 64);  s += __shfl_xor(s, 2, 64);
                s += __shfl_xor(s, 4, 64);  s += __shfl_xor(s, 8, 64);
                float rd = 1.f / s;
                ppack[mt][r] = (unsigned)f2us(e0 * rd) | ((unsigned)f2us(e1 * rd) << 16);
            }
    }
    __syncthreads();
    {
        unsigned* Ap32 = (unsigned*)Ap;
        #pragma unroll
        for (int mt = 0; mt < 4; ++mt)
            #pragma unroll
            for (int r = 0; r < 4; ++r) {
                int row = mt * 16 + kq * 4 + r;
                Ap32[row * 68 + w * 16 + lrow] = ppack[mt][r];
            }
    }
    __syncthreads();

    f32x4 acc[4][4];
    #pragma unroll
    for (int i = 0; i < 4; ++i)
        #pragma unroll
        for (int j = 0; j < 4; ++j) acc[i][j] = (f32x4){0.f, 0.f, 0.f, 0.f};

    const bf16* wb = wmod + (size_t)b * CH * INNER + (size_t)(w * 64) * INNER;
    #pragma unroll 2
    for (int k0 = 0; k0 < 128; k0 += 32) {
        bf8v af[4], bfr[4];
        #pragma unroll
        for (int t = 0; t < 4; ++t)
            af[t] = *(const bf8v*)&Ap[(t * 16 + lrow) * 136 + k0 + kq * 8];
        #pragma unroll
        for (int t = 0; t < 4; ++t)
            bfr[t] = *(const bf8v*)&wb[(size_t)(t * 16 + lrow) * 128 + k0 + kq * 8];
        #pragma unroll
        for (int mt = 0; mt < 4; ++mt)
            #pragma unroll
            for (int nt = 0; nt < 4; ++nt)
                acc[mt][nt] = __builtin_amdgcn_mfma_f32_16x16x32_bf16(
                    af[mt], bfr[nt], acc[mt][nt], 0, 0, 0);
    }

    #pragma unroll
    for (int nt = 0; nt < 4; ++nt) {
        float bv = bout[w * 64 + nt * 16 + lrow];
        #pragma unroll
        for (int mt = 0; mt < 4; ++mt)
            #pragma unroll
            for (int r = 0; r < 4; ++r) acc[mt][nt][r] += bv;
    }

    #pragma unroll
    for (int mt = 0; mt < 4; ++mt)
        #pragma unroll
        for (int r = 0; r < 4; ++r) {
            float s = 0.f, sq = 0.f;
            #pragma unroll
            for (int nt = 0; nt < 4; ++nt) {
                float v = acc[mt][nt][r];
                s += v; sq += v * v;
            }
            #pragma unroll
            for (int m = 1; m <= 8; m <<= 1) {
                s += __shfl_xor(s, m, 64);
                sq += __shfl_xor(sq, m, 64);
            }
            if (lrow == 0) {
                int row = mt * 16 + kq * 4 + r;
                st[w * 128 + row * 2] = s;
                st[w * 128 + row * 2 + 1] = sq;
            }
        }
    __syncthreads();
    if (tid < 64) {
        float s  = st[tid * 2]       + st[128 + tid * 2]
                 + st[256 + tid * 2] + st[384 + tid * 2];
        float sq = st[tid * 2 + 1]       + st[128 + tid * 2 + 1]
                 + st[256 + tid * 2 + 1] + st[384 + tid * 2 + 1];
        float m = s * (1.f / 256.f);
        float var = sq * (1.f / 256.f) - m * m;
        st[512 + tid * 2] = m;
        st[512 + tid * 2 + 1] = rsqrtf(var + 1e-5f);
    }
    __syncthreads();
    #pragma unroll
    for (int mt = 0; mt < 4; ++mt)
        #pragma unroll
        for (int r = 0; r < 4; ++r) {
            int row = mt * 16 + kq * 4 + r;
            float m = st[512 + row * 2], rs = st[512 + row * 2 + 1];
            #pragma unroll
            for (int nt = 0; nt < 4; ++nt)
                acc[mt][nt][r] = (acc[mt][nt][r] - m) * rs;
        }

    #pragma unroll 1
    for (int pr = 0; pr < 2; ++pr) {
        __syncthreads();
        if ((w >> 1) == pr) {
            #pragma unroll
            for (int mt = 0; mt < 4; ++mt)
                #pragma unroll
                for (int nt = 0; nt < 4; ++nt)
                    #pragma unroll
                    for (int r = 0; r < 4; ++r)
                        ct[((w & 1) * 64 + nt * 16 + lrow) * 68 + mt * 16 + kq * 4 + r]
                            = acc[mt][nt][r];
        }
        __syncthreads();
        #pragma unroll
        for (int i = 0; i < 8; ++i) {
            int idx = i * 256 + tid;
            int n4 = (idx & 15) * 4, cl = idx >> 4;
            size_t gi = ((size_t)b * CH + pr * 128 + cl) * NPOS + n0 + n4;
            f32x4 cv = *(const f32x4*)&ct[cl * 68 + n4];
            f32x4 xv = *(const f32x4*)&x[gi];
            __builtin_nontemporal_store(cv + xv, (f32x4*)&out[gi]);
        }
    }
}

// ---------------------------------------------------------------------------
extern "C" void kernel_launch(void* const* d_in, const int* in_sizes, int n_in,
                              void* d_out, int out_size, void* d_ws, size_t ws_size,
                              hipStream_t stream) {
    const float* x    = (const float*)d_in[0];   // [16,256,64,64]
    const float* Wqkv = (const float*)d_in[1];   // [384,256]
    const float* Wout = (const float*)d_in[2];   // [256,128]
    const float* bout = (const float*)d_in[3];   // [256]
    float* out = (float*)d_out;

    // workspace (~19.1 MB)
    char* ws = (char*)d_ws;
    float* ctxp   = (float*)ws;                      // 16*64*4*1056*4  = 17301504
    bf16*  wmod   = (bf16*)(ws + 17301504);          // 16*256*128*2    = 1048576
    bf16*  wqb    = (bf16*)(ws + 18350080);          // 384*256*2       = 196608
    float* wqs    = (float*)(ws + 18546688);         // 384*4           = 1536
    float* musr   = (float*)(ws + 18548224);         // 16*4096*2*4     = 524288

    void* args[] = { (void*)&x, (void*)&Wqkv, (void*)&Wout, (void*)&bout,
                     (void*)&out, (void*)&wqb, (void*)&wqs, (void*)&ctxp,
                     (void*)&wmod };
    hipError_t rc = hipLaunchCooperativeKernel((const void*)mega_kernel,
                                               dim3(1024), dim3(256),
                                               args, 0, stream);
    if (rc != hipSuccess) {
        (void)hipGetLastError();       // clear the error; use fallback pipeline
        prep_w_kernel<<<dim3(96), 256, 0, stream>>>(Wqkv, wqb, wqs);
        fused_qkv_kernel<<<dim3(64, BATCH), 256, 0, stream>>>(x, wqb, wqs, musr, ctxp);
        ctx_wmod_kernel<<<dim3(HEADS, BATCH, 2), 256, 0, stream>>>(ctxp, Wout, wmod);
        fused_out_kernel<<<dim3(64, BATCH), 256, 0, stream>>>(wqb, wqs, musr, wmod,
                                                              bout, x, out);
    }
}

// Round 9
// 184.741 us; speedup vs baseline: 4.4845x; 4.4845x over previous
//
#include <hip/hip_runtime.h>
#include <hip/hip_bf16.h>
#include <math.h>

// AttnBlock: B=16, C=256, H=W=64, heads=4, dim_head=32
#define BATCH 16
#define CH 256
#define NPOS 4096
#define INNER 128
#define HEADS 4
#define DH 32

typedef __hip_bfloat16 bf16;
typedef short bf8v __attribute__((ext_vector_type(8)));    // 8 bf16 (4 VGPRs)
typedef float f32x4 __attribute__((ext_vector_type(4)));

__device__ __forceinline__ float b2f(bf16 v) { return __bfloat162float(v); }
__device__ __forceinline__ float us2f(unsigned short u) {
    unsigned w = ((unsigned)u) << 16; float f; __builtin_memcpy(&f, &w, 4); return f;
}
__device__ __forceinline__ unsigned short f2us(float f) {
    bf16 h = __float2bfloat16(f); unsigned short u; __builtin_memcpy(&u, &h, 2); return u;
}
__device__ __forceinline__ bf16 f2b(float v) { return __float2bfloat16(v); }

// ---------------------------------------------------------------------------
// K0: Wqkv fp32 -> bf16, plus per-row colsum wqs[o] = sum_c bf16(W[o][c]).
// ---------------------------------------------------------------------------
__global__ __launch_bounds__(256)
void prep_w_kernel(const float* __restrict__ Wqkv, bf16* __restrict__ wqb,
                   float* __restrict__ wqs) {
    int idx = (blockIdx.x * 256 + threadIdx.x) * 4;
    float4 w = *(const float4*)&Wqkv[idx];
    ushort4 u;
    u.x = f2us(w.x); u.y = f2us(w.y); u.z = f2us(w.z); u.w = f2us(w.w);
    *(ushort4*)&wqb[idx] = u;
    float s4 = us2f(u.x) + us2f(u.y) + us2f(u.z) + us2f(u.w);
    #pragma unroll
    for (int m = 1; m <= 32; m <<= 1) s4 += __shfl_xor(s4, m, 64);
    if ((threadIdx.x & 63) == 0)
        wqs[blockIdx.x * 4 + (threadIdx.x >> 6)] = s4;
}

// ---------------------------------------------------------------------------
// K1: fused LN(deferred) + qkv GEMM + q-softmax + ctx partials via atomicAdd.
// ctx partials accumulate DIRECTLY into ctxu[b][h][1056] (270 KB, L2-resident,
// zeroed by host memsetAsync) -- the 17.3 MB ctxp write and the latency-bound
// 17.3 MB reduce pass are both gone.
// p stored packed u32 with head-dim permutation pi(d)=(d&15)*2+(d>>4).
// ---------------------------------------------------------------------------
__global__ __launch_bounds__(256)
void fused_qkv_kernel(const float* __restrict__ x, const bf16* __restrict__ wqb,
                      const float* __restrict__ wqs,
                      bf16* __restrict__ p, float* __restrict__ ctxu) {
    __shared__ char smem[36864];       // A[64][264] bf16 (33792) U 4x{ekt,vt}[32][72]
    __shared__ float stats[640];       // [64][4][2] partials + [64][2] mu/rs

    const int b = blockIdx.y, tile = blockIdx.x, n0 = tile * 64;
    const int tid = threadIdx.x;
    const int w = tid >> 6, lane = tid & 63;
    const int lrow = lane & 15, kq = lane >> 4;
    bf16* A = (bf16*)smem;             // [64][264]

    // ---- stage x tile (raw bf16): float4 along n, fp32 LN partial stats ----
    {
        const int nq = tid & 15, cp = tid >> 4;    // n-quad, c-pair group
        float s[4] = {0.f,0.f,0.f,0.f}, sq[4] = {0.f,0.f,0.f,0.f};
        #pragma unroll
        for (int i = 0; i < 8; ++i) {
            int c0 = cp * 2 + 32 * i;
            const float* xp = x + ((size_t)b * CH + c0) * NPOS + n0 + nq * 4;
            float4 fa = *(const float4*)xp;
            float4 fb = *(const float4*)(xp + NPOS);
            #pragma unroll
            for (int j = 0; j < 4; ++j) {
                float va = (&fa.x)[j], vb = (&fb.x)[j];
                s[j] += va + vb; sq[j] += va * va + vb * vb;
                *(unsigned*)&A[(nq * 4 + j) * 264 + c0] =
                    (unsigned)f2us(va) | ((unsigned)f2us(vb) << 16);
            }
        }
        #pragma unroll
        for (int j = 0; j < 4; ++j) {
            s[j]  += __shfl_xor(s[j], 16, 64);  sq[j] += __shfl_xor(sq[j], 16, 64);
            s[j]  += __shfl_xor(s[j], 32, 64);  sq[j] += __shfl_xor(sq[j], 32, 64);
            if (lane < 16) {
                stats[(nq * 4 + j) * 8 + w * 2]     = s[j];
                stats[(nq * 4 + j) * 8 + w * 2 + 1] = sq[j];
            }
        }
    }
    __syncthreads();
    if (tid < 64) {
        float s  = stats[tid*8] + stats[tid*8+2] + stats[tid*8+4] + stats[tid*8+6];
        float sq = stats[tid*8+1] + stats[tid*8+3] + stats[tid*8+5] + stats[tid*8+7];
        float m = s * (1.f / 256.f);
        float var = sq * (1.f / 256.f) - m * m;
        stats[512 + tid * 2] = m;
        stats[512 + tid * 2 + 1] = rsqrtf(var + 1e-5f);
    }
    __syncthreads();   // A (raw) + stats visible; A read-only until v-epilogue

    ushort4 ekp[4][2];                 // exp(k) bf16-packed, lives k-phase -> v-phase
    float se0 = 0.f, se1 = 0.f;

    for (int ph = 0; ph < 3; ++ph) {   // q, k, v
        const bf16* wp = wqb + (size_t)(ph * 128 + w * 32) * 256;
        const float cs0 = wqs[ph * 128 + w * 32 + lrow];
        const float cs1 = wqs[ph * 128 + w * 32 + 16 + lrow];
        f32x4 acc[4][2];
        #pragma unroll
        for (int i = 0; i < 4; ++i) {
            acc[i][0] = (f32x4){0.f,0.f,0.f,0.f};
            acc[i][1] = (f32x4){0.f,0.f,0.f,0.f};
        }
        #pragma unroll 4
        for (int k0 = 0; k0 < 256; k0 += 32) {
            bf8v af[4], bfr[2];
            #pragma unroll
            for (int t = 0; t < 4; ++t)
                af[t] = *(const bf8v*)&A[(t * 16 + lrow) * 264 + k0 + kq * 8];
            #pragma unroll
            for (int t = 0; t < 2; ++t)
                bfr[t] = *(const bf8v*)&wp[(size_t)(t * 16 + lrow) * 256 + k0 + kq * 8];
            #pragma unroll
            for (int mt = 0; mt < 4; ++mt)
                #pragma unroll
                for (int nt = 0; nt < 2; ++nt)
                    acc[mt][nt] = __builtin_amdgcn_mfma_f32_16x16x32_bf16(
                        af[mt], bfr[nt], acc[mt][nt], 0, 0, 0);
        }

        if (ph == 0) {
            // q: correct -> softmax (in-register, head == wave) -> packed store
            unsigned* pg32 = (unsigned*)p;
            #pragma unroll
            for (int mt = 0; mt < 4; ++mt)
                #pragma unroll
                for (int r = 0; r < 4; ++r) {
                    int row = mt * 16 + kq * 4 + r;
                    float mu = stats[512 + row * 2], rsn = stats[512 + row * 2 + 1];
                    float e0 = __expf(b2f(f2b((acc[mt][0][r] - mu * cs0) * rsn)));
                    float e1 = __expf(b2f(f2b((acc[mt][1][r] - mu * cs1) * rsn)));
                    float s = e0 + e1;
                    s += __shfl_xor(s, 1, 64);  s += __shfl_xor(s, 2, 64);
                    s += __shfl_xor(s, 4, 64);  s += __shfl_xor(s, 8, 64);
                    float rd = 1.f / s;
                    pg32[(size_t)(b * NPOS + n0 + row) * 64 + w * 16 + lrow] =
                        (unsigned)f2us(e0 * rd) | ((unsigned)f2us(e1 * rd) << 16);
                }
        } else if (ph == 1) {
            // k: correct -> exp -> bf16 pack (kept in regs); sumexp from the
            // SAME rounded values (ctx/se rounding cancels)
            se0 = 0.f; se1 = 0.f;
            #pragma unroll
            for (int mt = 0; mt < 4; ++mt) {
                ushort4 u0, u1;
                unsigned short q_;
                #pragma unroll
                for (int r = 0; r < 4; ++r) {
                    int row = mt * 16 + kq * 4 + r;
                    float mu = stats[512 + row * 2], rsn = stats[512 + row * 2 + 1];
                    q_ = f2us(__expf(b2f(f2b((acc[mt][0][r] - mu * cs0) * rsn))));
                    se0 += us2f(q_); (&u0.x)[r] = q_;
                    q_ = f2us(__expf(b2f(f2b((acc[mt][1][r] - mu * cs1) * rsn))));
                    se1 += us2f(q_); (&u1.x)[r] = q_;
                }
                ekp[mt][0] = u0; ekp[mt][1] = u1;
            }
            se0 += __shfl_xor(se0, 16, 64); se0 += __shfl_xor(se0, 32, 64);
            se1 += __shfl_xor(se1, 16, 64); se1 += __shfl_xor(se1, 32, 64);
        } else {
            // v: correct -> bf16; A is dead after this barrier
            __syncthreads();
            bf16* ekt = (bf16*)(smem + w * 9216);          // [32][72] head w
            bf16* vt  = (bf16*)(smem + w * 9216 + 4608);   // [32][72]
            #pragma unroll
            for (int mt = 0; mt < 4; ++mt)
                #pragma unroll
                for (int nt = 0; nt < 2; ++nt) {
                    float csx = nt ? cs1 : cs0;
                    ushort4 vv;
                    #pragma unroll
                    for (int r = 0; r < 4; ++r) {
                        int row = mt * 16 + kq * 4 + r;
                        float mu = stats[512 + row * 2], rsn = stats[512 + row * 2 + 1];
                        (&vv.x)[r] = f2us((acc[mt][nt][r] - mu * csx) * rsn);
                    }
                    int d = nt * 16 + lrow, n = mt * 16 + kq * 4;
                    *(ushort4*)&vt[d * 72 + n]  = vv;
                    *(ushort4*)&ekt[d * 72 + n] = ekp[mt][nt];
                }
            // ctx partial: D[d][e] = sum_n ekt[d][n]*vt[e][n]  (per-wave data)
            f32x4 cacc[2][2];
            cacc[0][0] = (f32x4){0.f,0.f,0.f,0.f}; cacc[0][1] = cacc[0][0];
            cacc[1][0] = cacc[0][0];               cacc[1][1] = cacc[0][0];
            #pragma unroll
            for (int ks = 0; ks < 2; ++ks) {
                bf8v a2[2], bv2[2];
                a2[0]  = *(const bf8v*)&ekt[lrow * 72 + ks * 32 + kq * 8];
                a2[1]  = *(const bf8v*)&ekt[(16 + lrow) * 72 + ks * 32 + kq * 8];
                bv2[0] = *(const bf8v*)&vt[lrow * 72 + ks * 32 + kq * 8];
                bv2[1] = *(const bf8v*)&vt[(16 + lrow) * 72 + ks * 32 + kq * 8];
                #pragma unroll
                for (int mt2 = 0; mt2 < 2; ++mt2)
                    #pragma unroll
                    for (int nt2 = 0; nt2 < 2; ++nt2)
                        cacc[mt2][nt2] = __builtin_amdgcn_mfma_f32_16x16x32_bf16(
                            a2[mt2], bv2[nt2], cacc[mt2][nt2], 0, 0, 0);
            }
            // accumulate into ctxu[b][h][1056] with device-scope atomics
            float* pb = ctxu + ((size_t)(b * HEADS + w)) * 1056;
            #pragma unroll
            for (int mt2 = 0; mt2 < 2; ++mt2)
                #pragma unroll
                for (int nt2 = 0; nt2 < 2; ++nt2)
                    #pragma unroll
                    for (int r = 0; r < 4; ++r) {
                        int d = mt2 * 16 + kq * 4 + r, e = nt2 * 16 + lrow;
                        atomicAdd(&pb[d * 32 + e], cacc[mt2][nt2][r]);
                    }
            if (kq == 0) {
                atomicAdd(&pb[1024 + lrow], se0);
                atomicAdd(&pb[1024 + 16 + lrow], se1);
            }
        }
    }
}

// ---------------------------------------------------------------------------
// K3: wmod from ctxu (270 KB, L2/L3-resident -- no reduce pass needed).
// grid (4 h, 16 b, 2 c-halves), 256 threads.
// wmod[c][pi(h,d)] = (sum_e Wout[c][h*32+e]*ctx[d][e])*SCALE/se[d], pi-packed.
// ---------------------------------------------------------------------------
__global__ __launch_bounds__(256)
void ctx_wmod_kernel(const float* __restrict__ ctxu, const float* __restrict__ Wout,
                     bf16* __restrict__ wmod) {
    __shared__ float cs[1056];
    int h = blockIdx.x, b = blockIdx.y, ch = blockIdx.z;
    int tid = threadIdx.x;

    #pragma unroll
    for (int i = 0; i < 2; ++i) {
        int s = i * 256 + tid;
        if (s < 264)
            *(f32x4*)&cs[s * 4] =
                *(const f32x4*)(ctxu + ((size_t)(b * HEADS + h)) * 1056 + s * 4);
    }
    __syncthreads();

    int c = ch * 128 + (tid >> 1);
    int dh = tid & 1;                       // which 8-d' group
    const float* wr = Wout + (size_t)c * INNER + h * DH;
    float wv[32];
    #pragma unroll
    for (int i = 0; i < 8; ++i) {
        float4 t = *(const float4*)&wr[i * 4];
        wv[i * 4] = t.x; wv[i * 4 + 1] = t.y; wv[i * 4 + 2] = t.z; wv[i * 4 + 3] = t.w;
    }
    const float SCALE = 4.3158341e-05f;     // 1/(4096*sqrt(32))
    unsigned* wm32 = (unsigned*)(wmod + ((size_t)b * CH + c) * INNER + h * DH);
    #pragma unroll
    for (int dd = 0; dd < 8; ++dd) {
        int d1 = dh * 8 + dd, d2 = d1 + 16;
        const float* c1 = &cs[d1 * 32];
        const float* c2 = &cs[d2 * 32];
        float s1 = 0.f, s2 = 0.f;
        #pragma unroll
        for (int e4 = 0; e4 < 8; ++e4) {
            f32x4 t1 = *(const f32x4*)&c1[e4 * 4];
            f32x4 t2 = *(const f32x4*)&c2[e4 * 4];
            #pragma unroll
            for (int j = 0; j < 4; ++j) {
                s1 += wv[e4 * 4 + j] * t1[j];
                s2 += wv[e4 * 4 + j] * t2[j];
            }
        }
        float v1 = s1 * SCALE / cs[1024 + d1];
        float v2 = s2 * SCALE / cs[1024 + d2];
        wm32[d1] = (unsigned)f2us(v1) | ((unsigned)f2us(v2) << 16);
    }
}

// ---------------------------------------------------------------------------
// K4: fused y-GEMM + bias + channel LN + residual (R6 structure: p staged via
// uint4, wmod B-frags from L2, single 256B non-temporal out bursts).
// ---------------------------------------------------------------------------
__global__ __launch_bounds__(256)
void fused_out_kernel(const bf16* __restrict__ p, const bf16* __restrict__ wmod,
                      const float* __restrict__ bout, const float* __restrict__ x,
                      float* __restrict__ out) {
    __shared__ char lds[37376];
    bf16* Ap = (bf16*)lds;                 // [64][136] = 17408 B (union: ct)
    float* ct = (float*)lds;               // [128][68] f32 = 34816 B
    float* st = (float*)(lds + 34816);     // 640 floats

    const int b = blockIdx.y, n0 = blockIdx.x * 64;
    const int tid = threadIdx.x;
    const int w = tid >> 6, lane = tid & 63;
    const int lrow = lane & 15, kq = lane >> 4;

    // stage Ap = p tile [64][128] via uint4
    {
        const uint4* pg = (const uint4*)p;
        unsigned* A32 = (unsigned*)Ap;
        #pragma unroll
        for (int i = 0; i < 4; ++i) {
            int idx = i * 256 + tid;
            int c4 = idx & 15, n = idx >> 4;
            uint4 u = pg[(size_t)(b * NPOS + n0 + n) * 16 + c4];
            *(uint4*)(A32 + n * 68 + c4 * 4) = u;
        }
    }
    __syncthreads();

    f32x4 acc[4][4];
    #pragma unroll
    for (int i = 0; i < 4; ++i)
        #pragma unroll
        for (int j = 0; j < 4; ++j) acc[i][j] = (f32x4){0.f, 0.f, 0.f, 0.f};

    const bf16* wb = wmod + (size_t)b * CH * INNER + (size_t)(w * 64) * INNER;
    #pragma unroll 2
    for (int k0 = 0; k0 < 128; k0 += 32) {
        bf8v af[4], bfr[4];
        #pragma unroll
        for (int t = 0; t < 4; ++t)
            af[t] = *(const bf8v*)&Ap[(t * 16 + lrow) * 136 + k0 + kq * 8];
        #pragma unroll
        for (int t = 0; t < 4; ++t)
            bfr[t] = *(const bf8v*)&wb[(size_t)(t * 16 + lrow) * 128 + k0 + kq * 8];
        #pragma unroll
        for (int mt = 0; mt < 4; ++mt)
            #pragma unroll
            for (int nt = 0; nt < 4; ++nt)
                acc[mt][nt] = __builtin_amdgcn_mfma_f32_16x16x32_bf16(
                    af[mt], bfr[nt], acc[mt][nt], 0, 0, 0);
    }

    // bias add (before LN, matches reference)
    #pragma unroll
    for (int nt = 0; nt < 4; ++nt) {
        float bv = bout[w * 64 + nt * 16 + lrow];
        #pragma unroll
        for (int mt = 0; mt < 4; ++mt)
            #pragma unroll
            for (int r = 0; r < 4; ++r) acc[mt][nt][r] += bv;
    }

    // LN stats: per (mt,r) row, partial over this wave's 64 cols
    #pragma unroll
    for (int mt = 0; mt < 4; ++mt)
        #pragma unroll
        for (int r = 0; r < 4; ++r) {
            float s = 0.f, sq = 0.f;
            #pragma unroll
            for (int nt = 0; nt < 4; ++nt) {
                float v = acc[mt][nt][r];
                s += v; sq += v * v;
            }
            #pragma unroll
            for (int m = 1; m <= 8; m <<= 1) {
                s += __shfl_xor(s, m, 64);
                sq += __shfl_xor(sq, m, 64);
            }
            if (lrow == 0) {
                int row = mt * 16 + kq * 4 + r;
                st[w * 128 + row * 2] = s;
                st[w * 128 + row * 2 + 1] = sq;
            }
        }
    __syncthreads();
    if (tid < 64) {
        float s  = st[tid * 2]       + st[128 + tid * 2]
                 + st[256 + tid * 2] + st[384 + tid * 2];
        float sq = st[tid * 2 + 1]       + st[128 + tid * 2 + 1]
                 + st[256 + tid * 2 + 1] + st[384 + tid * 2 + 1];
        float m = s * (1.f / 256.f);
        float var = sq * (1.f / 256.f) - m * m;
        st[512 + tid * 2] = m;
        st[512 + tid * 2 + 1] = rsqrtf(var + 1e-5f);
    }
    __syncthreads();
    // normalize accs in place
    #pragma unroll
    for (int mt = 0; mt < 4; ++mt)
        #pragma unroll
        for (int r = 0; r < 4; ++r) {
            int row = mt * 16 + kq * 4 + r;
            float m = st[512 + row * 2], rs = st[512 + row * 2 + 1];
            #pragma unroll
            for (int nt = 0; nt < 4; ++nt)
                acc[mt][nt][r] = (acc[mt][nt][r] - m) * rs;
        }

    // 2 c-half passes: transpose full 64-n rows -> ONE 256B burst per row
    #pragma unroll 1
    for (int pr = 0; pr < 2; ++pr) {
        __syncthreads();
        if ((w >> 1) == pr) {          // waves {0,1} for c 0..127, {2,3} for 128..255
            #pragma unroll
            for (int mt = 0; mt < 4; ++mt)
                #pragma unroll
                for (int nt = 0; nt < 4; ++nt)
                    #pragma unroll
                    for (int r = 0; r < 4; ++r)
                        ct[((w & 1) * 64 + nt * 16 + lrow) * 68 + mt * 16 + kq * 4 + r]
                            = acc[mt][nt][r];
        }
        __syncthreads();
        #pragma unroll
        for (int i = 0; i < 8; ++i) {
            int idx = i * 256 + tid;       // 2048 float4 per pass
            int n4 = (idx & 15) * 4, cl = idx >> 4;       // cl 0..127
            size_t gi = ((size_t)b * CH + pr * 128 + cl) * NPOS + n0 + n4;
            f32x4 cv = *(const f32x4*)&ct[cl * 68 + n4];
            f32x4 xv = *(const f32x4*)&x[gi];
            __builtin_nontemporal_store(cv + xv, (f32x4*)&out[gi]);
        }
    }
}

// ---------------------------------------------------------------------------
extern "C" void kernel_launch(void* const* d_in, const int* in_sizes, int n_in,
                              void* d_out, int out_size, void* d_ws, size_t ws_size,
                              hipStream_t stream) {
    const float* x    = (const float*)d_in[0];   // [16,256,64,64]
    const float* Wqkv = (const float*)d_in[1];   // [384,256]
    const float* Wout = (const float*)d_in[2];   // [256,128]
    const float* bout = (const float*)d_in[3];   // [256]
    float* out = (float*)d_out;

    // workspace (~18.3 MB; ctxp eliminated)
    char* ws = (char*)d_ws;
    bf16*  p      = (bf16*)ws;                       // 16*4096*128*2 = 16777216
    float* ctxu   = (float*)(ws + 16777216);         // 16*4*1056*4   = 270336
    bf16*  wmod   = (bf16*)(ws + 17047552);          // 16*256*128*2  = 1048576
    bf16*  wqb    = (bf16*)(ws + 18096128);          // 384*256*2     = 196608
    float* wqs    = (float*)(ws + 18292736);         // 384*4         = 1536

    hipMemsetAsync(ctxu, 0, 270336, stream);
    prep_w_kernel<<<dim3(96), 256, 0, stream>>>(Wqkv, wqb, wqs);
    fused_qkv_kernel<<<dim3(64, BATCH), 256, 0, stream>>>(x, wqb, wqs, p, ctxu);
    ctx_wmod_kernel<<<dim3(HEADS, BATCH, 2), 256, 0, stream>>>(ctxu, Wout, wmod);
    fused_out_kernel<<<dim3(64, BATCH), 256, 0, stream>>>(p, wmod, bout, x, out);
}